// Round 5
// baseline (42.759 us; speedup 1.0000x reference)
//
#include <hip/hip_runtime.h>
#include <hip/hip_bf16.h>

typedef __attribute__((ext_vector_type(8))) short bf16x8;   // 8 bf16 (4 VGPRs)
typedef __attribute__((ext_vector_type(4))) float f32x4;    // MFMA accumulator

#define CA_EPS 1e-6f

__device__ __forceinline__ unsigned short f2bf(float f) {
  // round-to-nearest-even bf16
  unsigned u = __float_as_uint(f);
  u += 0x7fffu + ((u >> 16) & 1u);
  return (unsigned short)(u >> 16);
}

// Gate + L2-normalize each 128-float row, emit bf16. One launch covers both
// X (blocks [0, rowsX/8)) and Y (blocks above) -- 8 rows per 256-thread block,
// so the X/Y split is block-uniform (no divergence).
__global__ void __launch_bounds__(256) gate_norm_kernel(
    const float* __restrict__ X, const float* __restrict__ A1,
    const float* __restrict__ Y, const float* __restrict__ A2,
    unsigned short* __restrict__ outX, unsigned short* __restrict__ outY,
    int rowsX) {
  int row = (int)((blockIdx.x * 256 + threadIdx.x) >> 5);
  int l = threadIdx.x & 31;
  const float* src;
  const float* gate;
  unsigned short* dst;
  if (row < rowsX) {
    src = X; gate = A1; dst = outX;
  } else {
    src = Y; gate = A2; dst = outY; row -= rowsX;
  }
  const float4 x = *(const float4*)(src + (size_t)row * 128 + l * 4);
  const float4 a = *(const float4*)(gate + (size_t)row * 128 + l * 4);
  float g0 = x.x * a.x, g1 = x.y * a.y, g2 = x.z * a.z, g3 = x.w * a.w;
  float ss = g0 * g0 + g1 * g1 + g2 * g2 + g3 * g3;
#pragma unroll
  for (int off = 16; off; off >>= 1) ss += __shfl_xor(ss, off);
  float inv = 1.0f / sqrtf(fmaxf(ss, CA_EPS));
  ushort4 o;
  o.x = f2bf(g0 * inv);
  o.y = f2bf(g1 * inv);
  o.z = f2bf(g2 * inv);
  o.w = f2bf(g3 * inv);
  *(ushort4*)(dst + (size_t)row * 128 + l * 4) = o;
}

#define GLOAD_LDS16(g, l)                                        \
  __builtin_amdgcn_global_load_lds(                              \
      (const __attribute__((address_space(1))) void*)(g),        \
      (__attribute__((address_space(3))) void*)(l), 16, 0, 0)

// C[b][n][m] = sum_k Xn[b][n][k] * Yn[b][m][k]  (bf16, row-major, K=128 whole row)
// 64 rows x 256 cols per block; 8 waves (1x8 wave grid, 64x32 slab each),
// LDS 80 KB (A 16 KB + B 64 KB) -> 2 blocks/CU.
// MFMA operands SWAPPED (mfma(bf, af)): lane&15 -> X row (C row),
// (lane>>4)*4+reg -> Y row (C col) -- each lane holds 4 consecutive C columns,
// so the C write is global_store_dwordx4 (16 B/lane, 8 stores/thread) instead
// of 32 scalar dword stores.
// LDS XOR-swizzled (chunk ^= row&7) via pre-swizzled global source so the
// stride-256B ds_read_b128 fragment reads are bank-conflict-free (rule #21).
__global__ void __launch_bounds__(512, 4) cosine_gemm_kernel(
    const unsigned short* __restrict__ Xn,  // (B, 2048, 128) bf16
    const unsigned short* __restrict__ Yn,  // (B, 2048, 128) bf16
    float* __restrict__ C) {                // (B, 2048, 2048) f32
  __shared__ unsigned short ldsA[64 * 128];    // 16 KB
  __shared__ unsigned short ldsB[256 * 128];   // 64 KB

  const int tid = threadIdx.x;
  const int lane = tid & 63;
  const int w = tid >> 6;  // wave 0..7 = column slab (32 cols each)

  const int tn = blockIdx.x;  // 64-row slab of X / C rows (32 tiles)
  const int tm = blockIdx.y;  // 256-col slab of Y / C cols (8 tiles)
  const int b = blockIdx.z;

  // Tiles span the full row dimension (d=128) -> contiguous global blocks.
  const unsigned short* Asrc = Xn + ((size_t)b * 2048 + (size_t)tn * 64) * 128;
  const unsigned short* Bsrc = Yn + ((size_t)b * 2048 + (size_t)tm * 256) * 128;

  // Stage A: 1024 16B-chunks (2/thread); B: 4096 chunks (8/thread).
  // LDS dest linear (wave-uniform base + lane*16); global source chunk is
  // inverse-swizzled so LDS chunk p holds global chunk (p ^ (row&7)).
#pragma unroll
  for (int i = 0; i < 2; ++i) {
    int p = i * 512 + tid;
    int q = (p & ~15) | ((p & 15) ^ ((p >> 4) & 7));
    GLOAD_LDS16(Asrc + (size_t)q * 8, &ldsA[(i * 512 + w * 64) * 8]);
  }
#pragma unroll
  for (int i = 0; i < 8; ++i) {
    int p = i * 512 + tid;
    int q = (p & ~15) | ((p & 15) ^ ((p >> 4) & 7));
    GLOAD_LDS16(Bsrc + (size_t)q * 8, &ldsB[(i * 512 + w * 64) * 8]);
  }
  __syncthreads();

  f32x4 acc[4][2] = {};
  const int r16 = lane & 15;  // A-frag row = C row (swapped operands)
  const int kq = lane >> 4;   // k-quarter 0..3; also C col quad in epilogue

#pragma unroll
  for (int kk = 0; kk < 4; ++kk) {
    const int kc = kk * 4 + kq;  // 8-element K-chunk index (0..15)
    bf16x8 af[4], bfr[2];
#pragma unroll
    for (int mi = 0; mi < 4; ++mi) {
      int r = mi * 16 + r16;  // A row 0..63
      af[mi] = *(const bf16x8*)(&ldsA[r * 128 + ((kc ^ (r & 7)) * 8)]);
    }
#pragma unroll
    for (int ni = 0; ni < 2; ++ni) {
      int r = w * 32 + ni * 16 + r16;  // B row 0..255
      bfr[ni] = *(const bf16x8*)(&ldsB[r * 128 + ((kc ^ (r & 7)) * 8)]);
    }
    // Swapped operand order: lane&15 -> af's row (C row),
    // (lane>>4)*4 + reg -> bfr's row (C col).
#pragma unroll
    for (int mi = 0; mi < 4; ++mi)
#pragma unroll
      for (int ni = 0; ni < 2; ++ni)
        acc[mi][ni] = __builtin_amdgcn_mfma_f32_16x16x32_bf16(
            bfr[ni], af[mi], acc[mi][ni], 0, 0, 0);
  }

  // Each lane holds C[row = mi*16 + r16][col = ni*16 + kq*4 + (0..3)] -> x4 store.
  float* Cb = C + ((size_t)b * 2048 + (size_t)tn * 64) * 2048 +
              (size_t)tm * 256 + w * 32;
#pragma unroll
  for (int mi = 0; mi < 4; ++mi)
#pragma unroll
    for (int ni = 0; ni < 2; ++ni)
      *(f32x4*)(Cb + (size_t)(mi * 16 + r16) * 2048 + ni * 16 + kq * 4) =
          acc[mi][ni];
}

extern "C" void kernel_launch(void* const* d_in, const int* in_sizes, int n_in,
                              void* d_out, int out_size, void* d_ws, size_t ws_size,
                              hipStream_t stream) {
  const float* X  = (const float*)d_in[0];
  const float* Y  = (const float*)d_in[1];
  const float* A1 = (const float*)d_in[2];
  const float* A2 = (const float*)d_in[3];
  float* C = (float*)d_out;

  const int B = 8, N = 2048, M = 2048, D = 128;

  unsigned short* Xn = (unsigned short*)d_ws;    // (B,N,128) bf16
  unsigned short* Yn = Xn + (size_t)B * N * D;   // (B,M,128) bf16

  const int rowsX = B * N, rowsY = B * M;
  gate_norm_kernel<<<dim3((rowsX + rowsY) / 8), dim3(256), 0, stream>>>(
      X, A1, Y, A2, Xn, Yn, rowsX);
  cosine_gemm_kernel<<<dim3(N / 64, M / 256, B), dim3(512), 0, stream>>>(Xn, Yn, C);
}

// Round 6
// 40.149 us; speedup vs baseline: 1.0650x; 1.0650x over previous
//
#include <hip/hip_runtime.h>
#include <hip/hip_bf16.h>

typedef __attribute__((ext_vector_type(8))) short bf16x8;   // 8 bf16 (4 VGPRs)
typedef __attribute__((ext_vector_type(4))) float f32x4;    // MFMA accumulator

#define CA_EPS 1e-6f

__device__ __forceinline__ unsigned short f2bf(float f) {
  // round-to-nearest-even bf16
  unsigned u = __float_as_uint(f);
  u += 0x7fffu + ((u >> 16) & 1u);
  return (unsigned short)(u >> 16);
}

// Gate + L2-normalize each 128-float row, emit bf16. One launch covers both
// X (blocks [0, rowsX/8)) and Y (blocks above) -- 8 rows per 256-thread block,
// so the X/Y split is block-uniform (no divergence).
__global__ void __launch_bounds__(256) gate_norm_kernel(
    const float* __restrict__ X, const float* __restrict__ A1,
    const float* __restrict__ Y, const float* __restrict__ A2,
    unsigned short* __restrict__ outX, unsigned short* __restrict__ outY,
    int rowsX) {
  int row = (int)((blockIdx.x * 256 + threadIdx.x) >> 5);
  int l = threadIdx.x & 31;
  const float* src;
  const float* gate;
  unsigned short* dst;
  if (row < rowsX) {
    src = X; gate = A1; dst = outX;
  } else {
    src = Y; gate = A2; dst = outY; row -= rowsX;
  }
  const float4 x = *(const float4*)(src + (size_t)row * 128 + l * 4);
  const float4 a = *(const float4*)(gate + (size_t)row * 128 + l * 4);
  float g0 = x.x * a.x, g1 = x.y * a.y, g2 = x.z * a.z, g3 = x.w * a.w;
  float ss = g0 * g0 + g1 * g1 + g2 * g2 + g3 * g3;
#pragma unroll
  for (int off = 16; off; off >>= 1) ss += __shfl_xor(ss, off);
  float inv = 1.0f / sqrtf(fmaxf(ss, CA_EPS));
  ushort4 o;
  o.x = f2bf(g0 * inv);
  o.y = f2bf(g1 * inv);
  o.z = f2bf(g2 * inv);
  o.w = f2bf(g3 * inv);
  *(ushort4*)(dst + (size_t)row * 128 + l * 4) = o;
}

#define GLOAD_LDS16(g, l)                                        \
  __builtin_amdgcn_global_load_lds(                              \
      (const __attribute__((address_space(1))) void*)(g),        \
      (__attribute__((address_space(3))) void*)(l), 16, 0, 0)

// C[b][n][m] = sum_k Xn[b][n][k] * Yn[b][m][k]  (bf16, row-major, K=128 whole row)
// Multi-tile pipelined block: owns 256 rows x 256 cols = 4 iterations of a
// 64x256 tile. B-slab (64 KB) staged once, B-fragments hoisted to registers;
// A-tile (16 KB) double-buffered. Per iteration: issue next-A stage, compute,
// store, counted vmcnt(32) (stores stay in flight -- never drain to 0
// mid-loop), raw s_barrier. Stores issue every iteration so the write queue
// never runs dry (T3/T14 minimum 2-phase pattern).
// LDS 96 KB -> 1 block/CU, 8 waves. LDS XOR-swizzled (chunk ^= row&7) via
// pre-swizzled global source (rule #21) -- bank-conflict-free ds_read_b128.
__global__ void __launch_bounds__(512, 2) cosine_gemm_kernel(
    const unsigned short* __restrict__ Xn,  // (B, 2048, 128) bf16
    const unsigned short* __restrict__ Yn,  // (B, 2048, 128) bf16
    float* __restrict__ C) {                // (B, 2048, 2048) f32
  __shared__ unsigned short ldsB[256 * 128];     // 64 KB, staged once
  __shared__ unsigned short ldsA[2][64 * 128];   // 2 x 16 KB double buffer

  const int tid = threadIdx.x;
  const int lane = tid & 63;
  const int w = tid >> 6;  // wave 0..7 = column slab (32 cols each)

  const int gx = blockIdx.x;  // 256-row group (N/256 = 8)
  const int tm = blockIdx.y;  // 256-col group (M/256 = 8)
  const int b = blockIdx.z;

  const unsigned short* Asrc = Xn + ((size_t)b * 2048 + (size_t)gx * 256) * 128;
  const unsigned short* Bsrc = Yn + ((size_t)b * 2048 + (size_t)tm * 256) * 128;

  // Prologue: stage whole B-slab (4096 16B-chunks) + A tile 0 (1024 chunks).
  // LDS dest linear (wave-uniform base + lane*16); global source chunk is
  // inverse-swizzled so LDS chunk p holds global chunk (p ^ (row&7)).
#pragma unroll
  for (int i = 0; i < 8; ++i) {
    int p = i * 512 + tid;
    int q = (p & ~15) | ((p & 15) ^ ((p >> 4) & 7));
    GLOAD_LDS16(Bsrc + (size_t)q * 8, &ldsB[(i * 512 + w * 64) * 8]);
  }
#pragma unroll
  for (int i = 0; i < 2; ++i) {
    int p = i * 512 + tid;
    int q = (p & ~15) | ((p & 15) ^ ((p >> 4) & 7));
    GLOAD_LDS16(Asrc + (size_t)q * 8, &ldsA[0][(i * 512 + w * 64) * 8]);
  }
  __syncthreads();  // full drain once (prologue only)

  const int r16 = lane & 15;  // frag row (A) / frag col (B,C)
  const int kq = lane >> 4;   // k-quarter 0..3

  // Hoist B fragments -- iteration-invariant (8 ds_read_b128, then reg-resident).
  bf16x8 bfr[4][2];
#pragma unroll
  for (int kk = 0; kk < 4; ++kk) {
    int kc = kk * 4 + kq;
#pragma unroll
    for (int ni = 0; ni < 2; ++ni) {
      int r = w * 32 + ni * 16 + r16;
      bfr[kk][ni] = *(const bf16x8*)(&ldsB[r * 128 + ((kc ^ (r & 7)) * 8)]);
    }
  }

#pragma unroll
  for (int t = 0; t < 4; ++t) {
    // Issue next A-tile stage FIRST (2 gload_lds/thread); pin issue order so
    // the vmcnt(32) below counts these as the oldest outstanding VMEM ops.
    if (t < 3) {
#pragma unroll
      for (int i = 0; i < 2; ++i) {
        int p = i * 512 + tid;
        int q = (p & ~15) | ((p & 15) ^ ((p >> 4) & 7));
        GLOAD_LDS16(Asrc + (size_t)(t + 1) * 64 * 128 + (size_t)q * 8,
                    &ldsA[(t + 1) & 1][(i * 512 + w * 64) * 8]);
      }
      __builtin_amdgcn_sched_barrier(0);
    }

    // Compute 64x256 tile t from ldsA[t&1] (16 ds_read_b128 + 32 MFMA/wave).
    f32x4 acc[4][2] = {};
    const unsigned short* ldsAc = &ldsA[t & 1][0];
#pragma unroll
    for (int kk = 0; kk < 4; ++kk) {
      int kc = kk * 4 + kq;
      bf16x8 af[4];
#pragma unroll
      for (int mi = 0; mi < 4; ++mi) {
        int r = mi * 16 + r16;
        af[mi] = *(const bf16x8*)(&ldsAc[r * 128 + ((kc ^ (r & 7)) * 8)]);
      }
#pragma unroll
      for (int mi = 0; mi < 4; ++mi)
#pragma unroll
        for (int ni = 0; ni < 2; ++ni)
          acc[mi][ni] = __builtin_amdgcn_mfma_f32_16x16x32_bf16(
              af[mi], bfr[kk][ni], acc[mi][ni], 0, 0, 0);
    }

    // Store tile t (R4-proven epilogue). C/D layout: col = lane&15,
    // row = (lane>>4)*4 + reg. 32 dword stores/thread.
    float* Cb = C + ((size_t)b * 2048 + (size_t)gx * 256 + t * 64) * 2048 +
                (size_t)tm * 256 + w * 32;
#pragma unroll
    for (int mi = 0; mi < 4; ++mi)
#pragma unroll
      for (int j = 0; j < 4; ++j) {
        float* crow = Cb + (size_t)(mi * 16 + kq * 4 + j) * 2048 + r16;
#pragma unroll
        for (int ni = 0; ni < 2; ++ni) crow[ni * 16] = acc[mi][ni][j];
      }

    if (t < 3) {
      // Wait only for the 2 A-stage loads (oldest); the 32 stores of this
      // iteration may remain in flight across the barrier.
      asm volatile("s_waitcnt vmcnt(32)" ::: "memory");
      __builtin_amdgcn_sched_barrier(0);
      __builtin_amdgcn_s_barrier();
      __builtin_amdgcn_sched_barrier(0);
    }
  }
}

extern "C" void kernel_launch(void* const* d_in, const int* in_sizes, int n_in,
                              void* d_out, int out_size, void* d_ws, size_t ws_size,
                              hipStream_t stream) {
  const float* X  = (const float*)d_in[0];
  const float* Y  = (const float*)d_in[1];
  const float* A1 = (const float*)d_in[2];
  const float* A2 = (const float*)d_in[3];
  float* C = (float*)d_out;

  const int B = 8, N = 2048, M = 2048, D = 128;

  unsigned short* Xn = (unsigned short*)d_ws;    // (B,N,128) bf16
  unsigned short* Yn = Xn + (size_t)B * N * D;   // (B,M,128) bf16

  const int rowsX = B * N, rowsY = B * M;
  gate_norm_kernel<<<dim3((rowsX + rowsY) / 8), dim3(256), 0, stream>>>(
      X, A1, Y, A2, Xn, Yn, rowsX);
  cosine_gemm_kernel<<<dim3(N / 256, M / 256, B), dim3(512), 0, stream>>>(Xn, Yn, C);
}

// Round 7
// 38.032 us; speedup vs baseline: 1.1243x; 1.0557x over previous
//
#include <hip/hip_runtime.h>
#include <hip/hip_bf16.h>

typedef __attribute__((ext_vector_type(8))) short bf16x8;   // 8 bf16 (4 VGPRs)
typedef __attribute__((ext_vector_type(4))) float f32x4;    // MFMA accumulator

#define CA_EPS 1e-6f

__device__ __forceinline__ unsigned short f2bf(float f) {
  // round-to-nearest-even bf16
  unsigned u = __float_as_uint(f);
  u += 0x7fffu + ((u >> 16) & 1u);
  return (unsigned short)(u >> 16);
}

// Gate + L2-normalize each 128-float row, emit bf16. One launch covers both
// X (blocks [0, rowsX/8)) and Y (blocks above) -- 8 rows per 256-thread block,
// so the X/Y split is block-uniform (no divergence).
__global__ void __launch_bounds__(256) gate_norm_kernel(
    const float* __restrict__ X, const float* __restrict__ A1,
    const float* __restrict__ Y, const float* __restrict__ A2,
    unsigned short* __restrict__ outX, unsigned short* __restrict__ outY,
    int rowsX) {
  int row = (int)((blockIdx.x * 256 + threadIdx.x) >> 5);
  int l = threadIdx.x & 31;
  const float* src;
  const float* gate;
  unsigned short* dst;
  if (row < rowsX) {
    src = X; gate = A1; dst = outX;
  } else {
    src = Y; gate = A2; dst = outY; row -= rowsX;
  }
  const float4 x = *(const float4*)(src + (size_t)row * 128 + l * 4);
  const float4 a = *(const float4*)(gate + (size_t)row * 128 + l * 4);
  float g0 = x.x * a.x, g1 = x.y * a.y, g2 = x.z * a.z, g3 = x.w * a.w;
  float ss = g0 * g0 + g1 * g1 + g2 * g2 + g3 * g3;
#pragma unroll
  for (int off = 16; off; off >>= 1) ss += __shfl_xor(ss, off);
  float inv = 1.0f / sqrtf(fmaxf(ss, CA_EPS));
  ushort4 o;
  o.x = f2bf(g0 * inv);
  o.y = f2bf(g1 * inv);
  o.z = f2bf(g2 * inv);
  o.w = f2bf(g3 * inv);
  *(ushort4*)(dst + (size_t)row * 128 + l * 4) = o;
}

#define GLOAD_LDS16(g, l)                                        \
  __builtin_amdgcn_global_load_lds(                              \
      (const __attribute__((address_space(1))) void*)(g),        \
      (__attribute__((address_space(3))) void*)(l), 16, 0, 0)

// C[b][n][m] = sum_k Xn[b][n][k] * Yn[b][m][k]  (bf16, row-major, K=128 whole row)
// R4 structure (proven 39.7us): 64 rows x 256 cols per block; 8 waves
// (1x8 wave grid, 64x32 slab each), LDS 80 KB (A 16 KB + B 64 KB), 2 blocks/CU.
// NEW: 1D grid with XCD-major swizzle -- XCD = batch (id & 7). Each XCD's L2
// (4 MB) then holds its batch's ENTIRE operand set (2.1 MB bf16), so all A/B
// panel re-reads are local L2 hits instead of cross-XCD L3 traffic competing
// with the C-store drain. nwg = 2048 % 8 == 0 -> bijective mapping.
// LDS XOR-swizzled (chunk ^= row&7) via pre-swizzled global source so the
// stride-256B ds_read_b128 fragment reads are bank-conflict-free (rule #21).
__global__ void __launch_bounds__(512, 4) cosine_gemm_kernel(
    const unsigned short* __restrict__ Xn,  // (B, 2048, 128) bf16
    const unsigned short* __restrict__ Yn,  // (B, 2048, 128) bf16
    float* __restrict__ C) {                // (B, 2048, 2048) f32
  __shared__ unsigned short ldsA[64 * 128];    // 16 KB
  __shared__ unsigned short ldsB[256 * 128];   // 64 KB

  const int tid = threadIdx.x;
  const int lane = tid & 63;
  const int w = tid >> 6;  // wave 0..7 = column slab (32 cols each)

  // XCD-major decomposition: XCD = batch, panels within batch stay local.
  const int id = blockIdx.x;
  const int b = id & 7;        // batch == XCD (round-robin dispatch)
  const int p = id >> 3;       // 256 panel tiles per batch
  const int tn = p & 31;       // 64-row slab of X / C rows (32 tiles)
  const int tm = p >> 5;       // 256-col slab of Y / C cols (8 tiles)

  // Tiles span the full row dimension (d=128) -> contiguous global blocks.
  const unsigned short* Asrc = Xn + ((size_t)b * 2048 + (size_t)tn * 64) * 128;
  const unsigned short* Bsrc = Yn + ((size_t)b * 2048 + (size_t)tm * 256) * 128;

  // Stage A: 1024 16B-chunks (2/thread); B: 4096 chunks (8/thread).
  // LDS dest linear (wave-uniform base + lane*16); global source chunk is
  // inverse-swizzled so LDS chunk p holds global chunk (p ^ (row&7)).
#pragma unroll
  for (int i = 0; i < 2; ++i) {
    int pp = i * 512 + tid;
    int q = (pp & ~15) | ((pp & 15) ^ ((pp >> 4) & 7));
    GLOAD_LDS16(Asrc + (size_t)q * 8, &ldsA[(i * 512 + w * 64) * 8]);
  }
#pragma unroll
  for (int i = 0; i < 8; ++i) {
    int pp = i * 512 + tid;
    int q = (pp & ~15) | ((pp & 15) ^ ((pp >> 4) & 7));
    GLOAD_LDS16(Bsrc + (size_t)q * 8, &ldsB[(i * 512 + w * 64) * 8]);
  }
  __syncthreads();

  f32x4 acc[4][2] = {};
  const int r16 = lane & 15;  // frag row (A) / frag col (B,C)
  const int kq = lane >> 4;   // k-quarter 0..3

#pragma unroll
  for (int kk = 0; kk < 4; ++kk) {
    const int kc = kk * 4 + kq;  // 8-element K-chunk index (0..15)
    bf16x8 af[4], bfr[2];
#pragma unroll
    for (int mi = 0; mi < 4; ++mi) {
      int r = mi * 16 + r16;  // A row 0..63
      af[mi] = *(const bf16x8*)(&ldsA[r * 128 + ((kc ^ (r & 7)) * 8)]);
    }
#pragma unroll
    for (int ni = 0; ni < 2; ++ni) {
      int r = w * 32 + ni * 16 + r16;  // B row 0..255
      bfr[ni] = *(const bf16x8*)(&ldsB[r * 128 + ((kc ^ (r & 7)) * 8)]);
    }
#pragma unroll
    for (int mi = 0; mi < 4; ++mi)
#pragma unroll
      for (int ni = 0; ni < 2; ++ni)
        acc[mi][ni] = __builtin_amdgcn_mfma_f32_16x16x32_bf16(
            af[mi], bfr[ni], acc[mi][ni], 0, 0, 0);
  }

  // C/D layout (m89-verified): col = lane&15, row = (lane>>4)*4 + reg.
  float* Cb = C + ((size_t)b * 2048 + (size_t)tn * 64) * 2048 +
              (size_t)tm * 256 + w * 32;
#pragma unroll
  for (int mi = 0; mi < 4; ++mi) {
#pragma unroll
    for (int j = 0; j < 4; ++j) {
      float* crow = Cb + (size_t)(mi * 16 + kq * 4 + j) * 2048 + r16;
#pragma unroll
      for (int ni = 0; ni < 2; ++ni) crow[ni * 16] = acc[mi][ni][j];
    }
  }
}

extern "C" void kernel_launch(void* const* d_in, const int* in_sizes, int n_in,
                              void* d_out, int out_size, void* d_ws, size_t ws_size,
                              hipStream_t stream) {
  const float* X  = (const float*)d_in[0];
  const float* Y  = (const float*)d_in[1];
  const float* A1 = (const float*)d_in[2];
  const float* A2 = (const float*)d_in[3];
  float* C = (float*)d_out;

  const int B = 8, N = 2048, M = 2048, D = 128;

  unsigned short* Xn = (unsigned short*)d_ws;    // (B,N,128) bf16
  unsigned short* Yn = Xn + (size_t)B * N * D;   // (B,M,128) bf16

  const int rowsX = B * N, rowsY = B * M;
  gate_norm_kernel<<<dim3((rowsX + rowsY) / 8), dim3(256), 0, stream>>>(
      X, A1, Y, A2, Xn, Yn, rowsX);
  // 1D grid: 2048 blocks, XCD = id & 7 = batch.
  cosine_gemm_kernel<<<dim3((N / 64) * (M / 256) * B), dim3(512), 0, stream>>>(
      Xn, Yn, C);
}